// Round 1
// baseline (123.844 us; speedup 1.0000x reference)
//
#include <hip/hip_runtime.h>
#include <hip/hip_bf16.h>

// GCN layer, N=8192 nodes, E=262144 edges, D_IN=D_OUT=256.
// out = adj_norm @ (X @ W^T + b)   (valid since adj_norm rows sum to 1)
// adj = dedup'd edge set (bitmap) + I;  deg = popcount(row)+1.

#define NNODES 8192
#define DFEAT  256
#define WORDS_PER_ROW (NNODES / 32)   // 256 u32 per bitmap row

// ---------------- kernel 1: scatter edges into bitmap ----------------
__global__ __launch_bounds__(256) void scatter_edges(
    const int* __restrict__ ei, int E, unsigned* __restrict__ bitmap) {
  int e = blockIdx.x * 256 + threadIdx.x;
  if (e < E) {
    int s = ei[e];          // edge_index[0][e]
    int d = ei[E + e];      // edge_index[1][e]
    atomicOr(&bitmap[(size_t)s * WORDS_PER_ROW + (d >> 5)], 1u << (d & 31));
  }
}

// ---------------- kernel 2: Y = X @ W^T + b  (fp32 tiled GEMM) -------
// X:[N,256] row-major, W:[256,256] row-major (Y[n,o] = sum_k X[n,k]*W[o,k] + b[o])
#define BM 64
#define BN 64
#define BK 16
__global__ __launch_bounds__(256) void gemm_bias(
    const float* __restrict__ X, const float* __restrict__ W,
    const float* __restrict__ bias, float* __restrict__ Y) {
  __shared__ float As[BK][BM + 4];   // +4 pad: keeps rows 16B-aligned, spreads banks
  __shared__ float Bs[BK][BN + 4];

  const int bm = blockIdx.x;         // 0..N/BM-1
  const int bn = blockIdx.y;         // 0..DFEAT/BN-1
  const int tid = threadIdx.x;
  const int tx = tid & 15;           // output col group
  const int ty = tid >> 4;           // output row group

  const int lm = tid >> 2;           // 0..63 : tile row loaded by this thread
  const int lk = (tid & 3) * 4;      // 0,4,8,12 : k offset (float4)

  const float* Aptr = X + (size_t)(bm * BM + lm) * DFEAT + lk;
  const float* Bptr = W + (size_t)(bn * BN + lm) * DFEAT + lk;

  float c[4][4] = {};

  for (int k0 = 0; k0 < DFEAT; k0 += BK) {
    float4 av = *(const float4*)(Aptr + k0);
    float4 bv = *(const float4*)(Bptr + k0);
    As[lk + 0][lm] = av.x; As[lk + 1][lm] = av.y;
    As[lk + 2][lm] = av.z; As[lk + 3][lm] = av.w;
    Bs[lk + 0][lm] = bv.x; Bs[lk + 1][lm] = bv.y;
    Bs[lk + 2][lm] = bv.z; Bs[lk + 3][lm] = bv.w;
    __syncthreads();
#pragma unroll
    for (int k = 0; k < BK; ++k) {
      float4 a = *(const float4*)&As[k][ty * 4];
      float4 b = *(const float4*)&Bs[k][tx * 4];
      c[0][0] += a.x * b.x; c[0][1] += a.x * b.y; c[0][2] += a.x * b.z; c[0][3] += a.x * b.w;
      c[1][0] += a.y * b.x; c[1][1] += a.y * b.y; c[1][2] += a.y * b.z; c[1][3] += a.y * b.w;
      c[2][0] += a.z * b.x; c[2][1] += a.z * b.y; c[2][2] += a.z * b.z; c[2][3] += a.z * b.w;
      c[3][0] += a.w * b.x; c[3][1] += a.w * b.y; c[3][2] += a.w * b.z; c[3][3] += a.w * b.w;
    }
    __syncthreads();
  }

  const int ocol = bn * BN + tx * 4;
  float4 b4 = *(const float4*)(bias + ocol);
#pragma unroll
  for (int i = 0; i < 4; ++i) {
    const int row = bm * BM + ty * 4 + i;
    float4 r;
    r.x = c[i][0] + b4.x; r.y = c[i][1] + b4.y;
    r.z = c[i][2] + b4.z; r.w = c[i][3] + b4.w;
    *(float4*)(Y + (size_t)row * DFEAT + ocol) = r;
  }
}

// ---------------- kernel 3: out[i] = (sum_{j in nbr(i)} Y[j] + Y[i]) / (deg) ----
// One 256-thread block per node row. Thread t owns feature channel t.
__global__ __launch_bounds__(256) void aggregate(
    const unsigned* __restrict__ bitmap, const float* __restrict__ Y,
    float* __restrict__ out) {
  __shared__ unsigned short list[NNODES];  // worst-case full row
  __shared__ int cnt;

  const int i = blockIdx.x;
  const int tid = threadIdx.x;
  if (tid == 0) cnt = 0;
  __syncthreads();

  unsigned w = bitmap[(size_t)i * WORDS_PER_ROW + tid];
  while (w) {
    int bit = __ffs(w) - 1;
    w &= w - 1;
    int pos = atomicAdd(&cnt, 1);
    list[pos] = (unsigned short)(tid * 32 + bit);
  }
  __syncthreads();

  const int n = cnt;
  float acc0 = 0.f, acc1 = 0.f, acc2 = 0.f, acc3 = 0.f;
  int k = 0;
  for (; k + 4 <= n; k += 4) {
    int j0 = list[k + 0], j1 = list[k + 1], j2 = list[k + 2], j3 = list[k + 3];
    acc0 += Y[(size_t)j0 * DFEAT + tid];
    acc1 += Y[(size_t)j1 * DFEAT + tid];
    acc2 += Y[(size_t)j2 * DFEAT + tid];
    acc3 += Y[(size_t)j3 * DFEAT + tid];
  }
  for (; k < n; ++k) acc0 += Y[(size_t)list[k] * DFEAT + tid];

  float self = Y[(size_t)i * DFEAT + tid];  // +I self loop
  float r = (acc0 + acc1 + acc2 + acc3 + self) / (float)(n + 1);
  out[(size_t)i * DFEAT + tid] = r;
}

extern "C" void kernel_launch(void* const* d_in, const int* in_sizes, int n_in,
                              void* d_out, int out_size, void* d_ws, size_t ws_size,
                              hipStream_t stream) {
  const float* x  = (const float*)d_in[0];
  const int*   ei = (const int*)d_in[1];
  const float* W  = (const float*)d_in[2];
  const float* b  = (const float*)d_in[3];
  float* out = (float*)d_out;

  const int E = in_sizes[1] / 2;

  // workspace layout: [0, 8MB) bitmap, [8MB, 16MB) Y
  unsigned* bitmap = (unsigned*)d_ws;
  float* Y = (float*)((char*)d_ws + (size_t)NNODES * WORDS_PER_ROW * 4);

  hipMemsetAsync(bitmap, 0, (size_t)NNODES * WORDS_PER_ROW * 4, stream);
  scatter_edges<<<(E + 255) / 256, 256, 0, stream>>>(ei, E, bitmap);
  gemm_bias<<<dim3(NNODES / BM, DFEAT / BN), 256, 0, stream>>>(x, W, b, Y);
  aggregate<<<NNODES, 256, 0, stream>>>(bitmap, Y, out);
}